// Round 3
// baseline (259.832 us; speedup 1.0000x reference)
//
#include <hip/hip_runtime.h>

// RefVisionPooler: data-driven 2x2 average pool on a 64x64 token grid.
//   out[b,o,:] = (sum_{s: idx(s)=o, !pad} hs[b,s,:]) / k^2 * sqrt(D)
//   mask[b,o]  = count(s: idx(s)=o) > 0        (padded tokens DO count toward mask)
//   idx(s)     = clamp(x)/k + (max_x/k) * clamp(y)/k,  max_x = max_s(clamp(x)) + 1
//
// Strategy: invert the data-driven token->cell map (cheap int atomics over 8K
// cells), then a pure coalesced gather — zero float atomics on the 151 MB
// stream. 2 dispatches:
//   k_fused_index: 1 block per batch — zero counts, reduce max_x in-block,
//                  __syncthreads, invert this batch's 4096 tokens. (The
//                  prep->build dependency is per-batch, so no global sync.)
//   k_pool:        the ~189 MB gather + scale + mask (memory-bound hot kernel).

static constexpr int Bc  = 8;
static constexpr int Sc  = 4096;
static constexpr int Dc  = 1152;
static constexpr int Oc  = 1024;
static constexpr int K   = 2;        // int(sqrt(Sc/Oc))
static constexpr int CAP = 8;        // recorded tokens per cell (data has exactly k^2=4)
static constexpr int DQ  = Dc / 4;   // float4 chunks per row = 288

// ---- kernel 1: per-batch {zero counts, max_x, invert map} --------------------
__global__ __launch_bounds__(256) void k_fused_index(
        const int* __restrict__ pix, const unsigned char* __restrict__ pad,
        int* __restrict__ counts, int* __restrict__ list) {
    int b = blockIdx.x;
    int* cnt_b = counts + b * Oc;

    // (a) zero this batch's counters (ws is re-poisoned 0xAA before every call)
    for (int i = threadIdx.x; i < Oc; i += blockDim.x) cnt_b[i] = 0;

    // (b) block-local reduction: max(clamp(x,0)) over this batch's tokens
    const int* p = pix + (size_t)b * Sc * 2;
    int m = 0;
    for (int s = threadIdx.x; s < Sc; s += blockDim.x)
        m = max(m, max(p[s * 2], 0));
    for (int off = 32; off > 0; off >>= 1)
        m = max(m, __shfl_down(m, off, 64));
    __shared__ int sm[4];
    __shared__ int s_gw;                    // grid width = (max_x+1)/K
    int wave = threadIdx.x >> 6;
    if ((threadIdx.x & 63) == 0) sm[wave] = m;
    __syncthreads();
    if (threadIdx.x == 0)
        s_gw = (max(max(sm[0], sm[1]), max(sm[2], sm[3])) + 1) / K;
    __syncthreads();                        // counts zeroed + s_gw ready
    int gw = s_gw;

    // (c) invert: token s -> cell o; record source rows (−1 for padded tokens,
    //     which still increment the count — mask semantics match segment_sum).
    const unsigned char* pd = pad + (size_t)b * Sc;
    for (int s = threadIdx.x; s < Sc; s += blockDim.x) {
        int x = max(p[s * 2], 0);
        int y = max(p[s * 2 + 1], 0);
        int o = x / K + gw * (y / K);
        if (o < 0 || o >= Oc) continue;     // segment_sum drops out-of-range ids
        int slot = atomicAdd(&cnt_b[o], 1);
        if (slot < CAP) list[(size_t)(b * Oc + o) * CAP + slot] = pd[s] ? -1 : s;
    }
}

// ---- kernel 2: the ~189 MB gather + scale + mask (memory-bound) --------------
__global__ __launch_bounds__(256) void k_pool(
        const float* __restrict__ hs, const int* __restrict__ counts,
        const int* __restrict__ list, float* __restrict__ out,
        float* __restrict__ mask) {
    int t = blockIdx.x * blockDim.x + threadIdx.x;
    if (t >= Bc * Oc * DQ) return;
    int dq   = t % DQ;
    int cell = t / DQ;                      // b*Oc + o
    int b    = cell >> 10;                  // / Oc

    int cnt_raw = counts[cell];             // wave-mostly-uniform -> cached
    if (dq == 0) mask[cell] = (cnt_raw > 0) ? 1.0f : 0.0f;
    int cnt = min(cnt_raw, CAP);

    const int* lst = list + (size_t)cell * CAP;
    const float* base = hs + (size_t)b * Sc * Dc + (size_t)dq * 4;
    float4 acc = {0.f, 0.f, 0.f, 0.f};
    for (int j = 0; j < cnt; ++j) {
        int s = lst[j];
        if (s < 0) continue;                // padded token contributes 0
        const float4 v = *reinterpret_cast<const float4*>(base + (size_t)s * Dc);
        acc.x += v.x; acc.y += v.y; acc.z += v.z; acc.w += v.w;
    }
    const float scale = 8.485281374238571f; // sqrt(1152) / k^2
    acc.x *= scale; acc.y *= scale; acc.z *= scale; acc.w *= scale;
    *reinterpret_cast<float4*>(out + (size_t)t * 4) = acc;
}

extern "C" void kernel_launch(void* const* d_in, const int* in_sizes, int n_in,
                              void* d_out, int out_size, void* d_ws, size_t ws_size,
                              hipStream_t stream) {
    const float*         hs  = (const float*)d_in[0];
    const int*           pix = (const int*)d_in[1];
    const unsigned char* pad = (const unsigned char*)d_in[2];
    // d_in[3] = output_length (device scalar); shape constants are compile-time.

    float* out  = (float*)d_out;
    float* mask = out + (size_t)Bc * Oc * Dc;   // tuple outputs concatenated flat

    // workspace (ints): [counts: B*Oc][list: B*Oc*CAP]
    int* counts = (int*)d_ws;
    int* list   = counts + Bc * Oc;

    k_fused_index<<<Bc, 256, 0, stream>>>(pix, pad, counts, list);
    k_pool<<<(Bc * Oc * DQ + 255) / 256, 256, 0, stream>>>(hs, counts, list, out, mask);
}

// Round 5
// 249.281 us; speedup vs baseline: 1.0423x; 1.0423x over previous
//
#include <hip/hip_runtime.h>

// RefVisionPooler: data-driven 2x2 average pool on a 64x64 token grid.
//   out[b,o,:] = (sum_{s: idx(s)=o, !pad} hs[b,s,:]) / k^2 * sqrt(D)
//   mask[b,o]  = count(s: idx(s)=o) > 0        (padded tokens DO count toward mask)
//   idx(s)     = clamp(x)/k + (max_x/k) * clamp(y)/k,  max_x = max_s(clamp(x)) + 1
//
// Strategy: invert the data-driven token->cell map (cheap int atomics over 8K
// cells), then a pure coalesced gather — zero float atomics on the 151 MB
// stream. 2 dispatches:
//   k_fused_index: 1 block per batch — zero counts, reduce max_x in-block,
//                  __syncthreads, invert this batch's 4096 tokens.
//   k_pool:        1 block per output cell — metadata is block-uniform (scalar
//                  loads), inner loop is a pure nontemporal float4 stream.

static constexpr int Bc  = 8;
static constexpr int Sc  = 4096;
static constexpr int Dc  = 1152;
static constexpr int Oc  = 1024;
static constexpr int K   = 2;        // int(sqrt(Sc/Oc))
static constexpr int CAP = 8;        // recorded tokens per cell (data has exactly k^2=4)
static constexpr int DQ  = Dc / 4;   // float4 chunks per row = 288

// native clang vector type — required by __builtin_nontemporal_load/store
// (HIP_vector_type float4 is a struct and is rejected).
typedef float f4 __attribute__((ext_vector_type(4)));

// ---- kernel 1: per-batch {zero counts, max_x, invert map} --------------------
__global__ __launch_bounds__(256) void k_fused_index(
        const int* __restrict__ pix, const unsigned char* __restrict__ pad,
        int* __restrict__ counts, int* __restrict__ list) {
    int b = blockIdx.x;
    int* cnt_b = counts + b * Oc;

    // (a) zero this batch's counters (ws is re-poisoned 0xAA before every call)
    for (int i = threadIdx.x; i < Oc; i += blockDim.x) cnt_b[i] = 0;

    // (b) block-local reduction: max(clamp(x,0)) over this batch's tokens
    const int* p = pix + (size_t)b * Sc * 2;
    int m = 0;
    for (int s = threadIdx.x; s < Sc; s += blockDim.x)
        m = max(m, max(p[s * 2], 0));
    for (int off = 32; off > 0; off >>= 1)
        m = max(m, __shfl_down(m, off, 64));
    __shared__ int sm[4];
    __shared__ int s_gw;                    // grid width = (max_x+1)/K
    int wave = threadIdx.x >> 6;
    if ((threadIdx.x & 63) == 0) sm[wave] = m;
    __syncthreads();
    if (threadIdx.x == 0)
        s_gw = (max(max(sm[0], sm[1]), max(sm[2], sm[3])) + 1) / K;
    __syncthreads();                        // counts zeroed + s_gw ready
    int gw = s_gw;

    // (c) invert: token s -> cell o; record source rows (−1 for padded tokens,
    //     which still increment the count — mask semantics match segment_sum).
    const unsigned char* pd = pad + (size_t)b * Sc;
    for (int s = threadIdx.x; s < Sc; s += blockDim.x) {
        int x = max(p[s * 2], 0);
        int y = max(p[s * 2 + 1], 0);
        int o = x / K + gw * (y / K);
        if (o < 0 || o >= Oc) continue;     // segment_sum drops out-of-range ids
        int slot = atomicAdd(&cnt_b[o], 1);
        if (slot < CAP) list[(size_t)(b * Oc + o) * CAP + slot] = pd[s] ? -1 : s;
    }
}

// ---- kernel 2: the ~189 MB gather + scale + mask (memory-bound) --------------
// One block per output cell: counts/list addresses are wave-uniform -> scalar
// loads; the d-loop is a clean streaming gather (no div/mod, no per-lane
// metadata traffic). Inputs/outputs are touched exactly once -> nontemporal.
__global__ __launch_bounds__(256) void k_pool(
        const float* __restrict__ hs, const int* __restrict__ counts,
        const int* __restrict__ list, float* __restrict__ out,
        float* __restrict__ mask) {
    int cell = blockIdx.x;                  // b*Oc + o
    int b    = cell >> 10;                  // / Oc

    int cnt_raw = counts[cell];             // uniform -> s_load
    if (threadIdx.x == 0) mask[cell] = (cnt_raw > 0) ? 1.0f : 0.0f;
    int cnt = min(cnt_raw, CAP);

    const int* lst = list + (size_t)cell * CAP;
    const float* base = hs + (size_t)b * Sc * Dc;
    float* po = out + (size_t)cell * Dc;
    const float scale = 8.485281374238571f; // sqrt(1152) / k^2

    // DQ=288 float4 chunks, 256 threads: chunk i and (for i<32) i+256.
    for (int i = threadIdx.x; i < DQ; i += 256) {
        f4 acc = {0.f, 0.f, 0.f, 0.f};
        for (int j = 0; j < cnt; ++j) {
            int s = lst[j];                 // uniform -> s_load
            if (s < 0) continue;            // padded token contributes 0
            const f4* ps = reinterpret_cast<const f4*>(base + (size_t)s * Dc) + i;
            f4 v = __builtin_nontemporal_load(ps);
            acc += v;
        }
        acc *= scale;
        __builtin_nontemporal_store(acc, reinterpret_cast<f4*>(po) + i);
    }
}

extern "C" void kernel_launch(void* const* d_in, const int* in_sizes, int n_in,
                              void* d_out, int out_size, void* d_ws, size_t ws_size,
                              hipStream_t stream) {
    const float*         hs  = (const float*)d_in[0];
    const int*           pix = (const int*)d_in[1];
    const unsigned char* pad = (const unsigned char*)d_in[2];
    // d_in[3] = output_length (device scalar); shape constants are compile-time.

    float* out  = (float*)d_out;
    float* mask = out + (size_t)Bc * Oc * Dc;   // tuple outputs concatenated flat

    // workspace (ints): [counts: B*Oc][list: B*Oc*CAP]
    int* counts = (int*)d_ws;
    int* list   = counts + Bc * Oc;

    k_fused_index<<<Bc, 256, 0, stream>>>(pix, pad, counts, list);
    k_pool<<<Bc * Oc, 256, 0, stream>>>(hs, counts, list, out, mask);
}